// Round 1
// baseline (1520.403 us; speedup 1.0000x reference)
//
#include <hip/hip_runtime.h>

// Problem constants (match reference)
#define NN   8192      // nodes
#define NE   524288    // edges
#define DH   16384     // 2N hidden
#define NOUT 32

// Persistent-kernel geometry: 1024 blocks x 256 thr.
// __launch_bounds__(256,4) -> VGPR<=128 -> 4 blocks/CU guaranteed -> all
// 1024 blocks co-resident on 256 CUs => custom grid barrier is safe.
#define NBLK 1024
#define NTHR 256
#define NTH_TOT (NBLK * NTHR)   // 262144 threads; 2 edges/thread

typedef float f32x4 __attribute__((ext_vector_type(4)));

struct Args {
    const float* data; const int* src; const int* dst;
    const float* W1; const float* b1; const float* W2; const float* b2;
    const float* W3; const float* b3; const float* Wa; const float* ba;
    const float* Wb; const float* bb;
    float* out;
    // workspace
    float* h1; float* h2; float* h3; float* v; float* y1; float* dinv;
    int* cnt; int* bar; int* row; int* cursor; int* blksum; int* srcs;
};

// Device-scope grid barrier, one fresh counter per sync point (zeroed by the
// launch-time memset, so no reset/generation logic is needed).
// Correctness on non-coherent per-XCD L2s:
//   __syncthreads(): compiler drains vmcnt -> all block stores are in L2
//                    (L1 is write-through).
//   release __threadfence(): buffer_wbl2 -> dirty L2 lines reach the
//                    device coherence point before the atomic arrive.
//   acquire __threadfence(): invalidates stale L1/L2 lines before reads.
__device__ __forceinline__ void gridbar(int* bar, int idx) {
    __syncthreads();
    if (threadIdx.x == 0) {
        __threadfence();                                  // release
        atomicAdd(&bar[idx], 1);
        while (__hip_atomic_load(&bar[idx], __ATOMIC_RELAXED,
                                 __HIP_MEMORY_SCOPE_AGENT) < NBLK)
            __builtin_amdgcn_s_sleep(2);
        __threadfence();                                  // acquire
    }
    __syncthreads();
}

__device__ __forceinline__ float wred(float a) {
#pragma unroll
    for (int off = 32; off > 0; off >>= 1) a += __shfl_down(a, off);
    return a;
}

__global__ __launch_bounds__(NTHR, 4) void k_fused(Args p) {
    const int tid  = blockIdx.x * NTHR + threadIdx.x;
    const int wave = tid >> 6;           // 0..4095
    const int lane = tid & 63;
    __shared__ int sm[NTHR];

    // ---- P0: h1 = x0 @ W1.T  +  degree histogram (edges read ONCE, src/dst
    //          kept in registers for the build phase) ----
    if (tid < NN) {
        float a = p.data[2 * tid], b = p.data[2 * tid + 1];
        f32x4 h;
#pragma unroll
        for (int c = 0; c < 4; ++c) h[c] = a * p.W1[2 * c] + b * p.W1[2 * c + 1];
        *(f32x4*)(p.h1 + 4 * tid) = h;
    }
    const int e0 = tid, e1 = tid + NTH_TOT;
    const int d0 = p.dst[e0], d1 = p.dst[e1];
    const int s0 = p.src[e0], s1 = p.src[e1];
    atomicAdd(&p.cnt[d0], 1);
    atomicAdd(&p.cnt[d1], 1);
    gridbar(p.bar, 0);

    // ---- P1: hierarchical scan, stage A: 32 blocks scan 256 counts each ----
    int myc = 0, pre = 0;
    if (blockIdx.x < 32) {
        int i = blockIdx.x * NTHR + threadIdx.x;
        myc = p.cnt[i];
        sm[threadIdx.x] = myc;
        __syncthreads();
        for (int off = 1; off < NTHR; off <<= 1) {
            int vsh = (threadIdx.x >= off) ? sm[threadIdx.x - off] : 0;
            __syncthreads();
            sm[threadIdx.x] += vsh;
            __syncthreads();
        }
        int incl = sm[threadIdx.x];
        pre = incl - myc;                                  // exclusive in-block
        if (threadIdx.x == NTHR - 1) p.blksum[blockIdx.x] = incl;
    }
    gridbar(p.bar, 1);

    // ---- P2: stage B: block offset (redundant 32-elem reduce) + row/cursor/dinv ----
    if (blockIdx.x < 32) {
        int boff = 0;
        for (int j = 0; j < (int)blockIdx.x; ++j) boff += p.blksum[j];
        int i = blockIdx.x * NTHR + threadIdx.x;
        int r = boff + pre;
        p.row[i] = r;
        p.cursor[i] = r;
        p.dinv[i] = rsqrtf((float)myc + 1.0f);             // self-loop folded in
        if (i == NN - 1) p.row[NN] = NE;
    }
    gridbar(p.bar, 2);

    // ---- P3: CSR build from register-held edges + fold dinv into h1
    //          (h1' = dinv[i]*h1[i] -> gathers need no per-edge dinv load) ----
    if (tid < NN) {
        float di = p.dinv[tid];
        f32x4 h = *(f32x4*)(p.h1 + 4 * tid);
        h *= di;
        *(f32x4*)(p.h1 + 4 * tid) = h;
    }
    { int q = atomicAdd(&p.cursor[d0], 1); p.srcs[q] = s0; }
    { int q = atomicAdd(&p.cursor[d1], 1); p.srcs[q] = s1; }
    gridbar(p.bar, 3);

    // ---- P4: layer1 aggregate (C=4) + relu + W2 -> h2' (pre-scaled) ----
    for (int k = 0; k < 2; ++k) {
        int i = 2 * wave + k;
        int beg = p.row[i], end = p.row[i + 1];
        float a0 = 0, a1 = 0, a2 = 0, a3 = 0;
        for (int q = beg + lane; q < end; q += 64) {
            int s = p.srcs[q];
            f32x4 hv = *(const f32x4*)(p.h1 + 4 * s);
            a0 += hv[0]; a1 += hv[1]; a2 += hv[2]; a3 += hv[3];
        }
        a0 = wred(a0); a1 = wred(a1); a2 = wred(a2); a3 = wred(a3);
        if (lane == 0) {
            float di = p.dinv[i];
            f32x4 hs = *(const f32x4*)(p.h1 + 4 * i);
            float x0 = fmaxf(di * (a0 + hs[0]) + p.b1[0], 0.0f);
            float x1 = fmaxf(di * (a1 + hs[1]) + p.b1[1], 0.0f);
            float x2 = fmaxf(di * (a2 + hs[2]) + p.b1[2], 0.0f);
            float x3 = fmaxf(di * (a3 + hs[3]) + p.b1[3], 0.0f);
            float o0 = x0 * p.W2[0] + x1 * p.W2[1] + x2 * p.W2[2] + x3 * p.W2[3];
            float o1 = x0 * p.W2[4] + x1 * p.W2[5] + x2 * p.W2[6] + x3 * p.W2[7];
            float2 o; o.x = di * o0; o.y = di * o1;
            *(float2*)(p.h2 + 2 * i) = o;
        }
    }
    gridbar(p.bar, 4);

    // ---- P5: layer2 aggregate (C=2) + relu + W3 -> h3' (pre-scaled) ----
    for (int k = 0; k < 2; ++k) {
        int i = 2 * wave + k;
        int beg = p.row[i], end = p.row[i + 1];
        float a0 = 0, a1 = 0;
        for (int q = beg + lane; q < end; q += 64) {
            int s = p.srcs[q];
            float2 hv = *(const float2*)(p.h2 + 2 * s);
            a0 += hv.x; a1 += hv.y;
        }
        a0 = wred(a0); a1 = wred(a1);
        if (lane == 0) {
            float di = p.dinv[i];
            float2 hs = *(const float2*)(p.h2 + 2 * i);
            float x0 = fmaxf(di * (a0 + hs.x) + p.b2[0], 0.0f);
            float x1 = fmaxf(di * (a1 + hs.y) + p.b2[1], 0.0f);
            p.h3[i] = di * (x0 * p.W3[0] + x1 * p.W3[1]);
        }
    }
    gridbar(p.bar, 5);

    // ---- P6: layer3 aggregate (C=1) -> v ----
    for (int k = 0; k < 2; ++k) {
        int i = 2 * wave + k;
        int beg = p.row[i], end = p.row[i + 1];
        float a0 = 0;
        for (int q = beg + lane; q < end; q += 64) a0 += p.h3[p.srcs[q]];
        a0 = wred(a0);
        if (lane == 0) p.v[i] = p.dinv[i] * (a0 + p.h3[i]) + p.b3[0];
    }
    gridbar(p.bar, 6);

    // ---- P7: y1 = tanh(Wa @ v + ba). 4 consecutive rows per wave share each
    //          v load; Wa streamed non-temporally (read exactly once). ----
    {
        const f32x4* vv = (const f32x4*)p.v;
        const float* wbase = p.Wa + (size_t)(4 * wave) * NN;
        float acc0 = 0, acc1 = 0, acc2 = 0, acc3 = 0;
#pragma unroll 2
        for (int it = 0; it < NN / 4 / 64; ++it) {        // 32 iters
            int idx = it * 64 + lane;
            f32x4 x  = vv[idx];
            f32x4 wA = __builtin_nontemporal_load((const f32x4*)wbase + idx);
            f32x4 wB = __builtin_nontemporal_load((const f32x4*)(wbase + NN) + idx);
            f32x4 wC = __builtin_nontemporal_load((const f32x4*)(wbase + 2 * NN) + idx);
            f32x4 wD = __builtin_nontemporal_load((const f32x4*)(wbase + 3 * NN) + idx);
            acc0 += wA[0] * x[0] + wA[1] * x[1] + wA[2] * x[2] + wA[3] * x[3];
            acc1 += wB[0] * x[0] + wB[1] * x[1] + wB[2] * x[2] + wB[3] * x[3];
            acc2 += wC[0] * x[0] + wC[1] * x[1] + wC[2] * x[2] + wC[3] * x[3];
            acc3 += wD[0] * x[0] + wD[1] * x[1] + wD[2] * x[2] + wD[3] * x[3];
        }
        acc0 = wred(acc0); acc1 = wred(acc1); acc2 = wred(acc2); acc3 = wred(acc3);
        if (lane == 0) {
            float4 bav = *(const float4*)(p.ba + 4 * wave);
            float4 o;
            o.x = tanhf(acc0 + bav.x);
            o.y = tanhf(acc1 + bav.y);
            o.z = tanhf(acc2 + bav.z);
            o.w = tanhf(acc3 + bav.w);
            *(float4*)(p.y1 + 4 * wave) = o;
        }
    }
    gridbar(p.bar, 7);

    // ---- P8: out = tanh(Wb @ y1 + bb), waves 0..31 ----
    if (tid < NOUT * 64) {
        int o = tid >> 6;
        const f32x4* wr = (const f32x4*)(p.Wb + (size_t)o * DH);
        const f32x4* yy = (const f32x4*)p.y1;
        float acc = 0.0f;
#pragma unroll 4
        for (int it = 0; it < DH / 4 / 64; ++it) {        // 64 iters
            int idx = it * 64 + lane;
            f32x4 w = wr[idx], x = yy[idx];
            acc += w[0] * x[0] + w[1] * x[1] + w[2] * x[2] + w[3] * x[3];
        }
        acc = wred(acc);
        if (lane == 0) p.out[o] = tanhf(acc + p.bb[o]);
    }
}

// ---------------------------------------------------------------------------

extern "C" void kernel_launch(void* const* d_in, const int* in_sizes, int n_in,
                              void* d_out, int out_size, void* d_ws, size_t ws_size,
                              hipStream_t stream) {
    (void)in_sizes; (void)n_in; (void)out_size; (void)ws_size;
    Args p;
    p.data = (const float*)d_in[0];
    const int* edge = (const int*)d_in[1];   // [2, E] int32 (harness-converted)
    p.src = edge;
    p.dst = edge + NE;
    p.W1 = (const float*)d_in[2];  p.b1 = (const float*)d_in[3];
    p.W2 = (const float*)d_in[4];  p.b2 = (const float*)d_in[5];
    p.W3 = (const float*)d_in[6];  p.b3 = (const float*)d_in[7];
    p.Wa = (const float*)d_in[8];  p.ba = (const float*)d_in[9];
    p.Wb = (const float*)d_in[10]; p.bb = (const float*)d_in[11];
    p.out = (float*)d_out;

    // workspace: floats first (keeps every f32x4 array 16B-aligned), ints after
    float* f = (float*)d_ws;
    p.h1   = f;  f += NN * 4;
    p.h2   = f;  f += NN * 2;
    p.h3   = f;  f += NN;
    p.v    = f;  f += NN;
    p.y1   = f;  f += DH;
    p.dinv = f;  f += NN;
    int* ip  = (int*)f;
    p.cnt    = ip;  ip += NN;
    p.bar    = ip;  ip += 8;        // 8 grid-barrier counters
    p.row    = ip;  ip += NN + 1;
    p.cursor = ip;  ip += NN;
    p.blksum = ip;  ip += 32;
    p.srcs   = ip;

    // zero histogram + barrier counters in one tiny memset
    hipMemsetAsync(p.cnt, 0, (size_t)(NN + 8) * sizeof(int), stream);
    hipLaunchKernelGGL(k_fused, dim3(NBLK), dim3(NTHR), 0, stream, p);
}

// Round 2
// 739.824 us; speedup vs baseline: 2.0551x; 2.0551x over previous
//
#include <hip/hip_runtime.h>

// Problem constants (match reference)
#define NN   8192      // nodes
#define NE   524288    // edges
#define DH   16384     // 2N hidden
#define NOUT 32

typedef float f32x4 __attribute__((ext_vector_type(4)));

// ---------------------------------------------------------------------------
// k_hist_h1: degree histogram (1M int atomics) + h1 = x0 @ W1.T (independent,
// fused to save a launch). Grid = NE/256 = 2048 blocks exactly.
// ---------------------------------------------------------------------------
__global__ __launch_bounds__(256) void k_hist_h1(const int* __restrict__ dst,
                                                 int* __restrict__ cnt,
                                                 const float* __restrict__ x0,
                                                 const float* __restrict__ W1,
                                                 float* __restrict__ h1) {
    int e = blockIdx.x * 256 + threadIdx.x;
    if (e < NN) {
        float a = x0[2 * e], b = x0[2 * e + 1];
        f32x4 h;
#pragma unroll
        for (int c = 0; c < 4; ++c) h[c] = a * W1[2 * c] + b * W1[2 * c + 1];
        *(f32x4*)(h1 + 4 * e) = h;
    }
    atomicAdd(&cnt[dst[e]], 1);
}

// ---------------------------------------------------------------------------
// k_scan: single block, 256 threads x 32 elems: exclusive scan of cnt ->
// row/cursor, plus dinv = rsqrt(deg+1) (self-loop folded in).
// ---------------------------------------------------------------------------
__global__ __launch_bounds__(256) void k_scan(const int* __restrict__ cnt,
                                              int* __restrict__ row,
                                              int* __restrict__ cursor,
                                              float* __restrict__ dinv) {
    __shared__ int sm[256];
    int t = threadIdx.x;
    int base = t * 32;
    int local[32];
    int sum = 0;
#pragma unroll
    for (int k = 0; k < 32; ++k) { local[k] = cnt[base + k]; sum += local[k]; }
    sm[t] = sum;
    __syncthreads();
    for (int off = 1; off < 256; off <<= 1) {
        int v = (t >= off) ? sm[t - off] : 0;
        __syncthreads();
        sm[t] += v;
        __syncthreads();
    }
    int pre = (t == 0) ? 0 : sm[t - 1];
#pragma unroll
    for (int k = 0; k < 32; ++k) {
        row[base + k] = pre;
        cursor[base + k] = pre;
        dinv[base + k] = rsqrtf((float)local[k] + 1.0f);
        pre += local[k];
    }
    if (t == 255) row[NN] = pre;   // == NE
}

// ---------------------------------------------------------------------------
// k_build: CSR scatter (1M int atomics) + prescale h1 *= dinv in place
// (h1' = dinv[i]*h1[i] -> gather loops need no per-edge dinv load).
// Each h1 element is touched by exactly one thread; srcs scatter never reads
// h1, so in-place is race-free. Grid = 2048 blocks exactly.
// ---------------------------------------------------------------------------
__global__ __launch_bounds__(256) void k_build(const int* __restrict__ src,
                                               const int* __restrict__ dst,
                                               int* __restrict__ cursor,
                                               int* __restrict__ srcs,
                                               const float* __restrict__ dinv,
                                               float* __restrict__ h1) {
    int e = blockIdx.x * 256 + threadIdx.x;
    if (e < NN) {
        float di = dinv[e];
        f32x4 h = *(f32x4*)(h1 + 4 * e);
        h *= di;
        *(f32x4*)(h1 + 4 * e) = h;
    }
    int p = atomicAdd(&cursor[dst[e]], 1);
    srcs[p] = src[e];
}

// ---------------------------------------------------------------------------
// Gather aggregation, one wave per node (4 nodes/block), no atomics.
// Math per layer: out[i] = b + dinv[i] * (sum_{s in N(i)} h'[s] + h'[i])
// where h' is the dinv-prescaled feature table; outputs stored prescaled.
// ---------------------------------------------------------------------------

__device__ __forceinline__ float wred(float a) {
#pragma unroll
    for (int off = 32; off > 0; off >>= 1) a += __shfl_down(a, off, 64);
    return a;
}

// layer1 agg (C=4) + relu + W2 -> h2' [NN*2]  (prescaled by dinv[i])
__global__ __launch_bounds__(256) void k_g4(const int* __restrict__ row,
                                            const int* __restrict__ srcs,
                                            const float* __restrict__ dinv,
                                            const float* __restrict__ h1,
                                            const float* __restrict__ b1,
                                            const float* __restrict__ W2,
                                            float* __restrict__ h2) {
    int wid = threadIdx.x >> 6, lane = threadIdx.x & 63;
    int i = blockIdx.x * 4 + wid;
    int beg = row[i], end = row[i + 1];
    float a0 = 0, a1 = 0, a2 = 0, a3 = 0;
    for (int p = beg + lane; p < end; p += 64) {
        int s = srcs[p];
        f32x4 hv = *(const f32x4*)(h1 + 4 * s);
        a0 += hv[0]; a1 += hv[1]; a2 += hv[2]; a3 += hv[3];
    }
    a0 = wred(a0); a1 = wred(a1); a2 = wred(a2); a3 = wred(a3);
    if (lane == 0) {
        float di = dinv[i];
        f32x4 hs = *(const f32x4*)(h1 + 4 * i);
        float x0 = fmaxf(di * (a0 + hs[0]) + b1[0], 0.0f);
        float x1 = fmaxf(di * (a1 + hs[1]) + b1[1], 0.0f);
        float x2 = fmaxf(di * (a2 + hs[2]) + b1[2], 0.0f);
        float x3 = fmaxf(di * (a3 + hs[3]) + b1[3], 0.0f);
        float o0 = x0 * W2[0] + x1 * W2[1] + x2 * W2[2] + x3 * W2[3];
        float o1 = x0 * W2[4] + x1 * W2[5] + x2 * W2[6] + x3 * W2[7];
        float2 o; o.x = di * o0; o.y = di * o1;
        *(float2*)(h2 + 2 * i) = o;
    }
}

// layer2 agg (C=2) + relu + W3 -> h3' [NN]  (prescaled by dinv[i])
__global__ __launch_bounds__(256) void k_g2(const int* __restrict__ row,
                                            const int* __restrict__ srcs,
                                            const float* __restrict__ dinv,
                                            const float* __restrict__ h2,
                                            const float* __restrict__ b2,
                                            const float* __restrict__ W3,
                                            float* __restrict__ h3) {
    int wid = threadIdx.x >> 6, lane = threadIdx.x & 63;
    int i = blockIdx.x * 4 + wid;
    int beg = row[i], end = row[i + 1];
    float a0 = 0, a1 = 0;
    for (int p = beg + lane; p < end; p += 64) {
        int s = srcs[p];
        float2 hv = *(const float2*)(h2 + 2 * s);
        a0 += hv.x; a1 += hv.y;
    }
    a0 = wred(a0); a1 = wred(a1);
    if (lane == 0) {
        float di = dinv[i];
        float2 hs = *(const float2*)(h2 + 2 * i);
        float x0 = fmaxf(di * (a0 + hs.x) + b2[0], 0.0f);
        float x1 = fmaxf(di * (a1 + hs.y) + b2[1], 0.0f);
        h3[i] = di * (x0 * W3[0] + x1 * W3[1]);
    }
}

// layer3 agg (C=1) -> v [NN]
__global__ __launch_bounds__(256) void k_g1(const int* __restrict__ row,
                                            const int* __restrict__ srcs,
                                            const float* __restrict__ dinv,
                                            const float* __restrict__ h3,
                                            const float* __restrict__ b3,
                                            float* __restrict__ v) {
    int wid = threadIdx.x >> 6, lane = threadIdx.x & 63;
    int i = blockIdx.x * 4 + wid;
    int beg = row[i], end = row[i + 1];
    float a0 = 0;
    for (int p = beg + lane; p < end; p += 64) a0 += h3[srcs[p]];
    a0 = wred(a0);
    if (lane == 0) {
        float di = dinv[i];
        v[i] = di * (a0 + h3[i]) + b3[0];
    }
}

// ---------------------------------------------------------------------------
// Trailing MLP: one wave per row, shuffle reduce, non-temporal weight stream.
// (Proven structure from the 748 us baseline — unchanged.)
// ---------------------------------------------------------------------------

__global__ __launch_bounds__(256) void k_mv1(const float* __restrict__ v,
                                             const float* __restrict__ Wa,
                                             const float* __restrict__ ba,
                                             float* __restrict__ y) {
    int wid  = threadIdx.x >> 6;
    int lane = threadIdx.x & 63;
    int j = blockIdx.x * 4 + wid;                 // row of Wa
    const f32x4* wr = (const f32x4*)(Wa + (size_t)j * NN);
    const f32x4* vv = (const f32x4*)v;
    float acc = 0.0f;
#pragma unroll 8
    for (int it = 0; it < (NN / 4) / 64; ++it) {  // 32 iters
        int idx = it * 64 + lane;                 // wave reads 1 KB contiguous
        f32x4 w = __builtin_nontemporal_load(&wr[idx]);   // Wa streamed once
        f32x4 x = vv[idx];
        acc += w[0] * x[0] + w[1] * x[1] + w[2] * x[2] + w[3] * x[3];
    }
    acc = wred(acc);
    if (lane == 0) y[j] = tanhf(acc + ba[j]);
}

__global__ __launch_bounds__(256) void k_mv2(const float* __restrict__ y,
                                             const float* __restrict__ Wb,
                                             const float* __restrict__ bb,
                                             float* __restrict__ out) {
    int wid  = threadIdx.x >> 6;
    int lane = threadIdx.x & 63;
    int o = blockIdx.x * 4 + wid;                 // row of Wb (32 rows -> 8 blocks)
    const f32x4* wr = (const f32x4*)(Wb + (size_t)o * DH);
    const f32x4* yy = (const f32x4*)y;
    float acc = 0.0f;
#pragma unroll 8
    for (int it = 0; it < (DH / 4) / 64; ++it) {  // 64 iters
        int idx = it * 64 + lane;
        f32x4 w = wr[idx];
        f32x4 x = yy[idx];
        acc += w[0] * x[0] + w[1] * x[1] + w[2] * x[2] + w[3] * x[3];
    }
    acc = wred(acc);
    if (lane == 0) out[o] = tanhf(acc + bb[o]);
}

// ---------------------------------------------------------------------------

extern "C" void kernel_launch(void* const* d_in, const int* in_sizes, int n_in,
                              void* d_out, int out_size, void* d_ws, size_t ws_size,
                              hipStream_t stream) {
    (void)in_sizes; (void)n_in; (void)out_size; (void)ws_size;
    const float* data = (const float*)d_in[0];
    const int*   edge = (const int*)d_in[1];       // [2, E] int32 (harness-converted)
    const float* W1   = (const float*)d_in[2];
    const float* b1   = (const float*)d_in[3];
    const float* W2   = (const float*)d_in[4];
    const float* b2   = (const float*)d_in[5];
    const float* W3   = (const float*)d_in[6];
    const float* b3   = (const float*)d_in[7];
    const float* Wa   = (const float*)d_in[8];
    const float* ba   = (const float*)d_in[9];
    const float* Wb   = (const float*)d_in[10];
    const float* bb   = (const float*)d_in[11];
    float* out = (float*)d_out;

    const int* src = edge;
    const int* dst = edge + NE;

    // workspace layout: floats first (keeps f32x4 arrays 16B-aligned), ints after
    float* f = (float*)d_ws;
    float* h1   = f;  f += NN * 4;
    float* h2   = f;  f += NN * 2;
    float* h3   = f;  f += NN;
    float* v    = f;  f += NN;
    float* y1   = f;  f += DH;
    float* dinv = f;  f += NN;
    int* ip    = (int*)f;
    int* cnt    = ip;  ip += NN;
    int* row    = ip;  ip += NN + 1;
    int* cursor = ip;  ip += NN;
    int* srcs   = ip;

    dim3 blk(256);
    dim3 gE(NE / 256);                // 2048 blocks (edge-domain)
    dim3 gW(NN / 4);                  // 2048 blocks (wave-per-node)

    hipMemsetAsync(cnt, 0, (size_t)NN * sizeof(int), stream);   // 32 KB

    k_hist_h1<<<gE, blk, 0, stream>>>(dst, cnt, data, W1, h1);
    k_scan   <<<dim3(1), blk, 0, stream>>>(cnt, row, cursor, dinv);
    k_build  <<<gE, blk, 0, stream>>>(src, dst, cursor, srcs, dinv, h1);
    k_g4     <<<gW, blk, 0, stream>>>(row, srcs, dinv, h1, b1, W2, h2);
    k_g2     <<<gW, blk, 0, stream>>>(row, srcs, dinv, h2, b2, W3, h3);
    k_g1     <<<gW, blk, 0, stream>>>(row, srcs, dinv, h3, b3, v);
    k_mv1    <<<dim3(DH / 4), blk, 0, stream>>>(v, Wa, ba, y1);
    k_mv2    <<<dim3(NOUT / 4), blk, 0, stream>>>(y1, Wb, bb, out);
}